// Round 3
// baseline (3074.798 us; speedup 1.0000x reference)
//
#include <hip/hip_runtime.h>
#include <math.h>

#define B_ 4
#define L_ 321
#define D_ 192
#define DI_ 384
#define E_ 768      // 2*DI
#define R_ 12
#define N_ 16
#define DEPTH_ 24
#define XD 44       // R + 2N

#define NC_ 21      // number of scan chunks
#define LC_ 16      // chunk length (NC_*LC_ >= L_)

__device__ __forceinline__ float silu_f(float x) { return x / (1.f + __expf(-x)); }

// ---------------- im2col for patch embed ----------------
// grid: B_*320 blocks, 256 threads; pm[b*320+p][768]
__global__ void im2col_kernel(const float* __restrict__ xs, const float* __restrict__ xt,
                              float* __restrict__ pm) {
    int p_all = blockIdx.x % 320;
    int b = blockIdx.x / 320;
    const float* src; int i, j, W;
    if (p_all < 64) { int p = p_all; i = p >> 3; j = p & 7; W = 128; src = xt + (size_t)b*3*128*128; }
    else            { int p = p_all - 64; i = p >> 4; j = p & 15; W = 256; src = xs + (size_t)b*3*256*256; }
    float* dst = pm + (size_t)blockIdx.x * 768;
    for (int m = threadIdx.x; m < 768; m += blockDim.x) {
        int c = m >> 8, rem = m & 255, pp = rem >> 4, qq = rem & 15;
        dst[m] = src[(size_t)(c*W + i*16 + pp)*W + j*16 + qq];
    }
}

// ---------------- scatter tokens + cls + pos; zero residual ----------------
// grid: B_*L_ blocks, 192 threads
__global__ void tok_scatter(const float* __restrict__ tokmat, const float* __restrict__ pb,
                            const float* __restrict__ cls, const float* __restrict__ pos,
                            float* __restrict__ hidden, float* __restrict__ residual) {
    int blk = blockIdx.x;
    int b = blk / L_, t = blk % L_;
    int d = threadIdx.x;
    size_t o = (size_t)(b*L_ + t)*D_ + d;
    residual[o] = 0.f;
    float v;
    if (t == 160) v = cls[d];
    else {
        int p = (t < 160) ? t : t - 1;
        v = tokmat[(size_t)(b*320 + p)*D_ + d] + pb[d];
    }
    hidden[o] = v + pos[t*D_ + d];
}

// ---------------- register-blocked GEMM: C = op(A) * B^T ----------------
// A: MxK row-major, B: NxK row-major. op(A) = AVG ? 0.5*(A0+A1) : A0.
// BK=16; threads (BN/TN, BM/TM) must be (16,16).
template<int BM, int BN, int TM, int TN, bool AVG>
__device__ __forceinline__ void gemm_body(const float* __restrict__ A0, const float* __restrict__ A1,
                                          const float* __restrict__ Bm, float* __restrict__ C,
                                          int M, int N, int K, int bx, int by) {
    constexpr int BK = 16;
    constexpr int TX = BN / TN;
    constexpr int TY = BM / TM;
    constexpr int THREADS = TX * TY;
    __shared__ float As[BK][BM + 4];
    __shared__ float Bs[BK][BN + 4];
    int tx = threadIdx.x, ty = threadIdx.y;
    int tid = ty * TX + tx;
    int m0 = by * BM;
    int n0 = bx * BN;
    float acc[TM][TN];
#pragma unroll
    for (int i = 0; i < TM; ++i)
#pragma unroll
        for (int j = 0; j < TN; ++j) acc[i][j] = 0.f;

    constexpr int ROWS_PER_PASS = THREADS / BK;   // 16
    constexpr int ALOADS = BM * BK / THREADS;
    constexpr int BLOADS = BN * BK / THREADS;
    int lk = tid & 15, lr = tid >> 4;

    for (int k0 = 0; k0 < K; k0 += BK) {
#pragma unroll
        for (int i = 0; i < ALOADS; ++i) {
            int m = lr + i * ROWS_PER_PASS;
            int gm = m0 + m;
            float v = (gm < M) ? A0[(size_t)gm*K + k0 + lk] : 0.f;
            if (AVG) { float v2 = (gm < M) ? A1[(size_t)gm*K + k0 + lk] : 0.f; v = 0.5f*(v + v2); }
            As[lk][m] = v;
        }
#pragma unroll
        for (int i = 0; i < BLOADS; ++i) {
            int n = lr + i * ROWS_PER_PASS;
            int gn = n0 + n;
            Bs[lk][n] = (gn < N) ? Bm[(size_t)gn*K + k0 + lk] : 0.f;
        }
        __syncthreads();
#pragma unroll
        for (int kk = 0; kk < BK; ++kk) {
            float ar[TM], br[TN];
#pragma unroll
            for (int i = 0; i < TM; ++i) ar[i] = As[kk][ty*TM + i];
#pragma unroll
            for (int j = 0; j < TN; ++j) br[j] = Bs[kk][tx*TN + j];
#pragma unroll
            for (int i = 0; i < TM; ++i)
#pragma unroll
                for (int j = 0; j < TN; ++j) acc[i][j] = fmaf(ar[i], br[j], acc[i][j]);
        }
        __syncthreads();
    }
#pragma unroll
    for (int i = 0; i < TM; ++i) {
        int gm = m0 + ty*TM + i;
        if (gm >= M) break;
#pragma unroll
        for (int j = 0; j < TN; ++j) {
            int gn = n0 + tx*TN + j;
            if (gn < N) C[(size_t)gm*N + gn] = acc[i][j];
        }
    }
}

template<int BM, int BN, int TM, int TN, bool AVG>
__global__ void gemm_single(const float* __restrict__ A0, const float* __restrict__ A1,
                            const float* __restrict__ Bm, float* __restrict__ C,
                            int M, int N, int K) {
    gemm_body<BM, BN, TM, TN, AVG>(A0, A1, Bm, C, M, N, K, blockIdx.x, blockIdx.y);
}

// dual: blockIdx.z selects (Af,Bf,Cf) or (Ab,Bb,Cb)
template<int BM, int BN, int TM, int TN>
__global__ void gemm_dual(const float* __restrict__ Af, const float* __restrict__ Bf, float* __restrict__ Cf,
                          const float* __restrict__ Ab, const float* __restrict__ Bb, float* __restrict__ Cb,
                          int M, int N, int K) {
    const float* A = blockIdx.z ? Ab : Af;
    const float* Bp = blockIdx.z ? Bb : Bf;
    float* C = blockIdx.z ? Cb : Cf;
    gemm_body<BM, BN, TM, TN, false>(A, (const float*)nullptr, Bp, C, M, N, K, blockIdx.x, blockIdx.y);
}

// ---------------- residual += hidden; hn = rmsnorm(residual)*normw ----------------
__global__ void prenorm_kernel(float* __restrict__ residual, const float* __restrict__ hidden,
                               const float* __restrict__ normw, float* __restrict__ hn) {
    int row = blockIdx.x;
    int tid = threadIdx.x;
    __shared__ float red[256];
    float v = 0.f;
    if (tid < D_) {
        v = residual[(size_t)row*D_ + tid] + hidden[(size_t)row*D_ + tid];
        residual[(size_t)row*D_ + tid] = v;
    }
    red[tid] = v * v;
    __syncthreads();
    for (int s = 128; s > 0; s >>= 1) { if (tid < s) red[tid] += red[tid + s]; __syncthreads(); }
    float scale = rsqrtf(red[0] / (float)D_ + 1e-5f);
    if (tid < D_) hn[(size_t)row*D_ + tid] = v * scale * normw[tid];
}

// ---------------- final: out = rmsnorm(hidden+residual)*normw_f ----------------
__global__ void final_kernel(const float* __restrict__ residual, const float* __restrict__ hidden,
                             const float* __restrict__ normw_f, float* __restrict__ out) {
    int row = blockIdx.x;
    int tid = threadIdx.x;
    __shared__ float red[256];
    float v = 0.f;
    if (tid < D_) v = residual[(size_t)row*D_ + tid] + hidden[(size_t)row*D_ + tid];
    red[tid] = v * v;
    __syncthreads();
    for (int s = 128; s > 0; s >>= 1) { if (tid < s) red[tid] += red[tid + s]; __syncthreads(); }
    float scale = rsqrtf(red[0] / (float)D_ + 1e-5f);
    if (tid < D_) out[(size_t)row*D_ + tid] = v * scale * normw_f[tid];
}

// ---------------- causal conv (k=4) + silu, both directions ----------------
__global__ void conv_kernel(const float* __restrict__ xz,
                            const float* __restrict__ cw, const float* __restrict__ cb,
                            const float* __restrict__ cwb, const float* __restrict__ cbb,
                            float* __restrict__ xc_f, float* __restrict__ xc_b) {
    int blk = blockIdx.x;
    int b = blk / L_, l = blk % L_;
    int d = threadIdx.x;
    const float* xbase = xz + (size_t)b*L_*E_ + d;   // x part = first DI_ of E_
    float acc = cb[d];
#pragma unroll
    for (int k = 0; k < 4; ++k) {
        int t = l - 3 + k;
        if (t >= 0) acc = fmaf(cw[d*4 + k], xbase[(size_t)t*E_], acc);
    }
    xc_f[(size_t)(b*L_ + l)*DI_ + d] = silu_f(acc);
    float accb = cbb[d];
#pragma unroll
    for (int k = 0; k < 4; ++k) {
        int t = l - 3 + k;
        if (t >= 0) accb = fmaf(cwb[d*4 + k], xbase[(size_t)(L_ - 1 - t)*E_], accb);
    }
    xc_b[(size_t)(b*L_ + l)*DI_ + d] = silu_f(accb);
}

// ---------------- delta = softplus(dt @ Wdt^T + bdt) ----------------
__global__ void delta_kernel(const float* __restrict__ xdbl_f, const float* __restrict__ xdbl_b,
                             const float* __restrict__ Wdt, const float* __restrict__ bdt,
                             const float* __restrict__ Wdtb, const float* __restrict__ bdtb,
                             float* __restrict__ delta_f, float* __restrict__ delta_b) {
    int row = blockIdx.x;
    int br  = blockIdx.y;
    int d   = threadIdx.x;
    const float* xd = br ? xdbl_b : xdbl_f;
    const float* W  = br ? Wdtb : Wdt;
    const float* bb = br ? bdtb : bdt;
    float* outp     = br ? delta_b : delta_f;
    __shared__ float dt[R_];
    if (d < R_) dt[d] = xd[(size_t)row*XD + d];
    __syncthreads();
    float acc = bb[d];
#pragma unroll
    for (int r = 0; r < R_; ++r) acc = fmaf(dt[r], W[d*R_ + r], acc);
    float sp = fmaxf(acc, 0.f) + log1pf(__expf(-fabsf(acc)));
    outp[(size_t)row*DI_ + d] = sp;
}

// ---------------- chunked parallel scan ----------------
__global__ void scan_part1(const float* __restrict__ xc_f, const float* __restrict__ xc_b,
                           const float* __restrict__ xdbl_f, const float* __restrict__ xdbl_b,
                           const float* __restrict__ delta_f, const float* __restrict__ delta_b,
                           const float* __restrict__ Alog, const float* __restrict__ Alogb,
                           float* __restrict__ hloc, float* __restrict__ aprod) {
    int c = blockIdx.x, b = blockIdx.y, br = blockIdx.z;
    int d = threadIdx.x;
    const float* xc = br ? xc_b : xc_f;
    const float* xd = br ? xdbl_b : xdbl_f;
    const float* de = br ? delta_b : delta_f;
    const float* Al = br ? Alogb : Alog;
    __shared__ float sdv[LC_][DI_];
    __shared__ float su[LC_][DI_];
    __shared__ float sB[LC_][N_];
    int lbeg = c * LC_;
    int lend = min(lbeg + LC_, L_);
    int len = lend - lbeg;
    for (int l2 = 0; l2 < len; ++l2) {
        size_t row = (size_t)b*L_ + lbeg + l2;
        sdv[l2][d] = de[row*DI_ + d];
        su[l2][d]  = xc[row*DI_ + d];
    }
    for (int idx = d; idx < len*N_; idx += DI_) {
        int l2 = idx >> 4, n = idx & 15;
        sB[l2][n] = xd[((size_t)b*L_ + lbeg + l2)*XD + R_ + n];
    }
    __syncthreads();
    float a[N_];
#pragma unroll
    for (int n = 0; n < N_; ++n) a[n] = -__expf(Al[d*N_ + n]);
    float h[N_], ap[N_];
#pragma unroll
    for (int n = 0; n < N_; ++n) { h[n] = 0.f; ap[n] = 1.f; }
    for (int l2 = 0; l2 < len; ++l2) {
        float dv = sdv[l2][d], u = su[l2][d], du = dv * u;
#pragma unroll
        for (int n = 0; n < N_; ++n) {
            float e = __expf(dv * a[n]);
            h[n] = fmaf(e, h[n], du * sB[l2][n]);
            ap[n] *= e;
        }
    }
    size_t base = (((size_t)(b*2 + br)*NC_ + c)*N_)*DI_ + d;
#pragma unroll
    for (int n = 0; n < N_; ++n) {
        hloc[base + (size_t)n*DI_]  = h[n];
        aprod[base + (size_t)n*DI_] = ap[n];
    }
}

__global__ void scan_combine(const float* __restrict__ hloc, const float* __restrict__ aprod,
                             float* __restrict__ hin) {
    int g = blockIdx.x * blockDim.x + threadIdx.x;   // over B_*2*N_*DI_
    int bb = g / (N_ * DI_);
    int rem = g % (N_ * DI_);
    float hrun = 0.f;
    for (int c = 0; c < NC_; ++c) {
        size_t idx = ((size_t)bb*NC_ + c)*N_*DI_ + rem;
        hin[idx] = hrun;
        hrun = fmaf(aprod[idx], hrun, hloc[idx]);
    }
}

__global__ void scan_part3(const float* __restrict__ xc_f, const float* __restrict__ xc_b,
                           const float* __restrict__ xdbl_f, const float* __restrict__ xdbl_b,
                           const float* __restrict__ delta_f, const float* __restrict__ delta_b,
                           const float* __restrict__ xz,
                           const float* __restrict__ Alog, const float* __restrict__ Alogb,
                           const float* __restrict__ Dpf, const float* __restrict__ Dpb,
                           const float* __restrict__ hin,
                           float* __restrict__ y_f, float* __restrict__ y_b) {
    int c = blockIdx.x, b = blockIdx.y, br = blockIdx.z;
    int d = threadIdx.x;
    const float* xc = br ? xc_b : xc_f;
    const float* xd = br ? xdbl_b : xdbl_f;
    const float* de = br ? delta_b : delta_f;
    const float* Al = br ? Alogb : Alog;
    const float* Dpp = br ? Dpb : Dpf;
    float* y = br ? y_b : y_f;
    __shared__ float sdv[LC_][DI_];
    __shared__ float su[LC_][DI_];
    __shared__ float sB[LC_][N_];
    __shared__ float sC[LC_][N_];
    int lbeg = c * LC_;
    int lend = min(lbeg + LC_, L_);
    int len = lend - lbeg;
    for (int l2 = 0; l2 < len; ++l2) {
        size_t row = (size_t)b*L_ + lbeg + l2;
        sdv[l2][d] = de[row*DI_ + d];
        su[l2][d]  = xc[row*DI_ + d];
    }
    for (int idx = d; idx < len*N_; idx += DI_) {
        int l2 = idx >> 4, n = idx & 15;
        size_t row = (size_t)b*L_ + lbeg + l2;
        sB[l2][n] = xd[row*XD + R_ + n];
        sC[l2][n] = xd[row*XD + R_ + N_ + n];
    }
    __syncthreads();
    float a[N_];
#pragma unroll
    for (int n = 0; n < N_; ++n) a[n] = -__expf(Al[d*N_ + n]);
    float h[N_];
    size_t hbase = (((size_t)(b*2 + br)*NC_ + c)*N_)*DI_ + d;
#pragma unroll
    for (int n = 0; n < N_; ++n) h[n] = hin[hbase + (size_t)n*DI_];
    float dpv = Dpp[d];
    for (int l2 = 0; l2 < len; ++l2) {
        float dv = sdv[l2][d], u = su[l2][d], du = dv * u;
        float yv = 0.f;
#pragma unroll
        for (int n = 0; n < N_; ++n) {
            float e = __expf(dv * a[n]);
            h[n] = fmaf(e, h[n], du * sB[l2][n]);
            yv = fmaf(h[n], sC[l2][n], yv);
        }
        yv = fmaf(dpv, u, yv);
        int lo = br ? (L_ - 1 - (lbeg + l2)) : (lbeg + l2);
        float zv = xz[((size_t)b*L_ + lo)*E_ + DI_ + d];
        y[((size_t)b*L_ + lo)*DI_ + d] = yv * silu_f(zv);
    }
}

extern "C" void kernel_launch(void* const* d_in, const int* in_sizes, int n_in,
                              void* d_out, int out_size, void* d_ws, size_t ws_size,
                              hipStream_t stream) {
    const float* xs     = (const float*)d_in[0];
    const float* xt     = (const float*)d_in[1];
    const float* pw     = (const float*)d_in[2];
    const float* pb     = (const float*)d_in[3];
    const float* cls    = (const float*)d_in[4];
    const float* pos    = (const float*)d_in[5];
    const float* Win    = (const float*)d_in[6];
    const float* convw  = (const float*)d_in[7];
    const float* convb  = (const float*)d_in[8];
    const float* Wx     = (const float*)d_in[9];
    const float* Wdt    = (const float*)d_in[10];
    const float* bdt    = (const float*)d_in[11];
    const float* Alog   = (const float*)d_in[12];
    const float* Dp     = (const float*)d_in[13];
    const float* convwb = (const float*)d_in[14];
    const float* convbb = (const float*)d_in[15];
    const float* Wxb    = (const float*)d_in[16];
    const float* Wdtb   = (const float*)d_in[17];
    const float* bdtb   = (const float*)d_in[18];
    const float* Alogb  = (const float*)d_in[19];
    const float* Dpb    = (const float*)d_in[20];
    const float* Wout   = (const float*)d_in[21];
    const float* normw  = (const float*)d_in[22];
    const float* normwf = (const float*)d_in[23];
    float* out = (float*)d_out;

    float* ws = (float*)d_ws;
    size_t off = 0;
    auto alloc = [&](size_t n) { float* p = ws + off; off += n; return p; };
    const size_t BL = (size_t)B_ * L_;
    const size_t CHNK = (size_t)B_ * 2 * NC_ * N_ * DI_;
    float* residual = alloc(BL * D_);
    float* hidden   = alloc(BL * D_);
    float* hn       = alloc(BL * D_);
    float* xzb      = alloc(BL * E_);
    float* xc_f     = alloc(BL * DI_);
    float* xc_b     = alloc(BL * DI_);
    float* xdbl_f   = alloc(BL * XD);
    float* xdbl_b   = alloc(BL * XD);
    float* delta_f  = alloc(BL * DI_);
    float* delta_b  = alloc(BL * DI_);
    float* y_f      = alloc(BL * DI_);
    float* y_b      = alloc(BL * DI_);
    float* hloc     = alloc(CHNK);
    float* aprod    = alloc(CHNK);
    float* hin      = alloc(CHNK);
    (void)ws_size; (void)in_sizes; (void)n_in; (void)out_size;

    // patch embed: reuse y_f/y_b (contiguous, unused until layers) as im2col
    // buffer, delta_f as token matrix. Sizes: pmat 4*320*768=983040 <= y_f+y_b
    // (986112); tokmat 4*320*192=245760 <= delta_f (493056).
    float* pmat   = y_f;
    float* tokmat = delta_f;
    im2col_kernel<<<dim3(B_ * 320), dim3(256), 0, stream>>>(xs, xt, pmat);
    gemm_single<32, 32, 2, 2, false><<<dim3(6, 40), dim3(16, 16), 0, stream>>>(
        pmat, (const float*)nullptr, pw, tokmat, B_ * 320, D_, 768);
    tok_scatter<<<dim3(B_ * L_), dim3(192), 0, stream>>>(tokmat, pb, cls, pos, hidden, residual);

    for (int layer = 0; layer < DEPTH_; ++layer) {
        const float* Win_l   = Win   + (size_t)layer * E_ * D_;
        const float* cw_l    = convw + (size_t)layer * DI_ * 4;
        const float* cb_l    = convb + (size_t)layer * DI_;
        const float* cwb_l   = convwb + (size_t)layer * DI_ * 4;
        const float* cbb_l   = convbb + (size_t)layer * DI_;
        const float* Wx_l    = Wx    + (size_t)layer * XD * DI_;
        const float* Wxb_l   = Wxb   + (size_t)layer * XD * DI_;
        const float* Wdt_l   = Wdt   + (size_t)layer * DI_ * R_;
        const float* Wdtb_l  = Wdtb  + (size_t)layer * DI_ * R_;
        const float* bdt_l   = bdt   + (size_t)layer * DI_;
        const float* bdtb_l  = bdtb  + (size_t)layer * DI_;
        const float* Alog_l  = Alog  + (size_t)layer * DI_ * N_;
        const float* Alogb_l = Alogb + (size_t)layer * DI_ * N_;
        const float* Dp_l    = Dp    + (size_t)layer * DI_;
        const float* Dpb_l   = Dpb   + (size_t)layer * DI_;
        const float* Wout_l  = Wout  + (size_t)layer * D_ * DI_;
        const float* normw_l = normw + (size_t)layer * D_;

        prenorm_kernel<<<dim3((int)BL), dim3(256), 0, stream>>>(residual, hidden, normw_l, hn);
        // in-proj: M=1284, N=768, K=192
        gemm_single<64, 64, 4, 4, false><<<dim3(E_ / 64, (int)((BL + 63) / 64)), dim3(16, 16), 0, stream>>>(
            hn, (const float*)nullptr, Win_l, xzb, (int)BL, E_, D_);
        conv_kernel<<<dim3((int)BL), dim3(DI_), 0, stream>>>(xzb, cw_l, cb_l, cwb_l, cbb_l, xc_f, xc_b);
        // xdbl (both dirs): M=1284, N=44, K=384
        gemm_dual<32, 32, 2, 2><<<dim3(2, (int)((BL + 31) / 32), 2), dim3(16, 16), 0, stream>>>(
            xc_f, Wx_l, xdbl_f, xc_b, Wxb_l, xdbl_b, (int)BL, XD, DI_);
        delta_kernel<<<dim3((int)BL, 2), dim3(DI_), 0, stream>>>(xdbl_f, xdbl_b, Wdt_l, bdt_l, Wdtb_l, bdtb_l, delta_f, delta_b);
        scan_part1<<<dim3(NC_, B_, 2), dim3(DI_), 0, stream>>>(xc_f, xc_b, xdbl_f, xdbl_b, delta_f, delta_b,
                                                               Alog_l, Alogb_l, hloc, aprod);
        scan_combine<<<dim3((B_*2*N_*DI_)/256), dim3(256), 0, stream>>>(hloc, aprod, hin);
        scan_part3<<<dim3(NC_, B_, 2), dim3(DI_), 0, stream>>>(xc_f, xc_b, xdbl_f, xdbl_b, delta_f, delta_b, xzb,
                                                               Alog_l, Alogb_l, Dp_l, Dpb_l, hin, y_f, y_b);
        // out-proj: M=1284, N=192, K=384, avg of fwd/bwd
        gemm_single<32, 32, 2, 2, true><<<dim3(6, (int)((BL + 31) / 32)), dim3(16, 16), 0, stream>>>(
            y_f, y_b, Wout_l, hidden, (int)BL, D_, DI_);
    }

    final_kernel<<<dim3((int)BL), dim3(256), 0, stream>>>(residual, hidden, normwf, out);
}

// Round 4
// 2151.848 us; speedup vs baseline: 1.4289x; 1.4289x over previous
//
#include <hip/hip_runtime.h>
#include <math.h>

#define B_ 4
#define L_ 321
#define D_ 192
#define DI_ 384
#define E_ 768      // 2*DI
#define R_ 12
#define N_ 16
#define DEPTH_ 24
#define XD 44       // R + 2N

#define NC_ 21      // number of scan chunks
#define LC_ 16      // chunk length (NC_*LC_ >= L_)

typedef __attribute__((ext_vector_type(8))) short bf16x8;
typedef __attribute__((ext_vector_type(4))) float f32x4;
typedef unsigned short ushort_t;

__device__ __forceinline__ float silu_f(float x) { return x / (1.f + __expf(-x)); }

__device__ __forceinline__ ushort_t f2bf(float x) {
    union { float f; unsigned u; } v; v.f = x;
    return (ushort_t)((v.u + 0x7fffu + ((v.u >> 16) & 1u)) >> 16);
}
__device__ __forceinline__ float bf2f(ushort_t h) {
    union { unsigned u; float f; } v; v.u = ((unsigned)h) << 16; return v.f;
}

// ---------------- f32 -> bf16 conversion (weights, once per launch) ----------------
__global__ void cvt_bf16(const float* __restrict__ src, ushort_t* __restrict__ dst, int n) {
    for (int i = blockIdx.x * blockDim.x + threadIdx.x; i < n; i += gridDim.x * blockDim.x)
        dst[i] = f2bf(src[i]);
}

// ---------------- im2col for patch embed (writes bf16) ----------------
__global__ void im2col_kernel(const float* __restrict__ xs, const float* __restrict__ xt,
                              ushort_t* __restrict__ pm) {
    int p_all = blockIdx.x % 320;
    int b = blockIdx.x / 320;
    const float* src; int i, j, W;
    if (p_all < 64) { int p = p_all; i = p >> 3; j = p & 7; W = 128; src = xt + (size_t)b*3*128*128; }
    else            { int p = p_all - 64; i = p >> 4; j = p & 15; W = 256; src = xs + (size_t)b*3*256*256; }
    ushort_t* dst = pm + (size_t)blockIdx.x * 768;
    for (int m = threadIdx.x; m < 768; m += blockDim.x) {
        int c = m >> 8, rem = m & 255, pp = rem >> 4, qq = rem & 15;
        dst[m] = f2bf(src[(size_t)(c*W + i*16 + pp)*W + j*16 + qq]);
    }
}

// ---------------- scatter tokens + cls + pos; zero residual ----------------
__global__ void tok_scatter(const float* __restrict__ tokmat, const float* __restrict__ pb,
                            const float* __restrict__ cls, const float* __restrict__ pos,
                            float* __restrict__ hidden, float* __restrict__ residual) {
    int blk = blockIdx.x;
    int b = blk / L_, t = blk % L_;
    int d = threadIdx.x;
    size_t o = (size_t)(b*L_ + t)*D_ + d;
    residual[o] = 0.f;
    float v;
    if (t == 160) v = cls[d];
    else {
        int p = (t < 160) ? t : t - 1;
        v = tokmat[(size_t)(b*320 + p)*D_ + d] + pb[d];
    }
    hidden[o] = v + pos[t*D_ + d];
}

// ---------------- MFMA bf16 GEMM: C(f32 MxN) = A(MxK) * B(NxK)^T ----------------
// No LDS: both operands K-contiguous; each lane loads bf16x8 fragments directly.
// AMODE 0: A is bf16. AMODE 1: A = 0.5*(Af0+Af1), f32 inputs converted on load.
// Wave grid: WM x WN waves per block, each wave computes (MFR*16) x (NFR*16).
template<int WM, int WN, int MFR, int NFR, int AMODE>
__device__ __forceinline__ void mfma_gemm_body(const ushort_t* __restrict__ A,
                                               const float* __restrict__ Af0,
                                               const float* __restrict__ Af1,
                                               const ushort_t* __restrict__ Bw,
                                               float* __restrict__ C,
                                               int M, int N, int K, int bx, int by) {
    constexpr int BM = WM * MFR * 16;
    constexpr int BN = WN * NFR * 16;
    int wave = threadIdx.x >> 6, lane = threadIdx.x & 63;
    int wr = wave / WN, wc = wave % WN;
    int m0 = by * BM + wr * MFR * 16;
    int n0 = bx * BN + wc * NFR * 16;
    int lrow = lane & 15;
    int lk   = (lane >> 4) * 8;

    f32x4 acc[MFR][NFR];
#pragma unroll
    for (int i = 0; i < MFR; ++i)
#pragma unroll
        for (int j = 0; j < NFR; ++j) acc[i][j] = (f32x4){0.f, 0.f, 0.f, 0.f};

    for (int k0 = 0; k0 < K; k0 += 32) {
        bf16x8 a[MFR], b[NFR];
#pragma unroll
        for (int i = 0; i < MFR; ++i) {
            int r = m0 + i*16 + lrow; r = min(r, M - 1);
            if (AMODE == 0) {
                a[i] = *(const bf16x8*)(A + (size_t)r*K + k0 + lk);
            } else {
                const float* p0 = Af0 + (size_t)r*K + k0 + lk;
                const float* p1 = Af1 + (size_t)r*K + k0 + lk;
                bf16x8 t;
#pragma unroll
                for (int j = 0; j < 8; ++j) t[j] = (short)f2bf(0.5f*(p0[j] + p1[j]));
                a[i] = t;
            }
        }
#pragma unroll
        for (int jn = 0; jn < NFR; ++jn) {
            int c = n0 + jn*16 + lrow; c = min(c, N - 1);
            b[jn] = *(const bf16x8*)(Bw + (size_t)c*K + k0 + lk);
        }
#pragma unroll
        for (int i = 0; i < MFR; ++i)
#pragma unroll
            for (int jn = 0; jn < NFR; ++jn)
                acc[i][jn] = __builtin_amdgcn_mfma_f32_16x16x32_bf16(a[i], b[jn], acc[i][jn], 0, 0, 0);
    }

    int crow = (lane >> 4) * 4;
    int ccol = lane & 15;
#pragma unroll
    for (int i = 0; i < MFR; ++i)
#pragma unroll
        for (int jn = 0; jn < NFR; ++jn) {
            int c = n0 + jn*16 + ccol;
            if (c >= N) continue;
#pragma unroll
            for (int j = 0; j < 4; ++j) {
                int r = m0 + i*16 + crow + j;
                if (r < M) C[(size_t)r*N + c] = acc[i][jn][j];
            }
        }
}

template<int WM, int WN, int MFR, int NFR, int AMODE>
__global__ __launch_bounds__(WM*WN*64) void mfma_gemm(const ushort_t* __restrict__ A,
                          const float* __restrict__ Af0, const float* __restrict__ Af1,
                          const ushort_t* __restrict__ Bw, float* __restrict__ C,
                          int M, int N, int K) {
    mfma_gemm_body<WM, WN, MFR, NFR, AMODE>(A, Af0, Af1, Bw, C, M, N, K, blockIdx.x, blockIdx.y);
}

// dual (fwd/bwd) variant for the xdbl GEMM: blockIdx.z picks the set
__global__ __launch_bounds__(256) void mfma_gemm_dual(const ushort_t* __restrict__ A0, const ushort_t* __restrict__ B0, float* __restrict__ C0,
                               const ushort_t* __restrict__ A1, const ushort_t* __restrict__ B1, float* __restrict__ C1,
                               int M, int N, int K) {
    if (blockIdx.z)
        mfma_gemm_body<4, 1, 1, 3, 0>(A1, nullptr, nullptr, B1, C1, M, N, K, blockIdx.x, blockIdx.y);
    else
        mfma_gemm_body<4, 1, 1, 3, 0>(A0, nullptr, nullptr, B0, C0, M, N, K, blockIdx.x, blockIdx.y);
}

// ---------------- residual += hidden; hn_bf = bf16(rmsnorm(residual)*normw) ----------------
__global__ void prenorm_kernel(float* __restrict__ residual, const float* __restrict__ hidden,
                               const float* __restrict__ normw, ushort_t* __restrict__ hn) {
    int row = blockIdx.x;
    int tid = threadIdx.x;
    __shared__ float red[256];
    float v = 0.f;
    if (tid < D_) {
        v = residual[(size_t)row*D_ + tid] + hidden[(size_t)row*D_ + tid];
        residual[(size_t)row*D_ + tid] = v;
    }
    red[tid] = v * v;
    __syncthreads();
    for (int s = 128; s > 0; s >>= 1) { if (tid < s) red[tid] += red[tid + s]; __syncthreads(); }
    float scale = rsqrtf(red[0] / (float)D_ + 1e-5f);
    if (tid < D_) hn[(size_t)row*D_ + tid] = f2bf(v * scale * normw[tid]);
}

// ---------------- final: out = rmsnorm(hidden+residual)*normw_f ----------------
__global__ void final_kernel(const float* __restrict__ residual, const float* __restrict__ hidden,
                             const float* __restrict__ normw_f, float* __restrict__ out) {
    int row = blockIdx.x;
    int tid = threadIdx.x;
    __shared__ float red[256];
    float v = 0.f;
    if (tid < D_) v = residual[(size_t)row*D_ + tid] + hidden[(size_t)row*D_ + tid];
    red[tid] = v * v;
    __syncthreads();
    for (int s = 128; s > 0; s >>= 1) { if (tid < s) red[tid] += red[tid + s]; __syncthreads(); }
    float scale = rsqrtf(red[0] / (float)D_ + 1e-5f);
    if (tid < D_) out[(size_t)row*D_ + tid] = v * scale * normw_f[tid];
}

// ---------------- causal conv (k=4) + silu, both directions (bf16 in/out) ----------------
__global__ void conv_kernel(const ushort_t* __restrict__ xz,
                            const float* __restrict__ cw, const float* __restrict__ cb,
                            const float* __restrict__ cwb, const float* __restrict__ cbb,
                            ushort_t* __restrict__ xc_f, ushort_t* __restrict__ xc_b) {
    int blk = blockIdx.x;
    int b = blk / L_, l = blk % L_;
    int d = threadIdx.x;
    const ushort_t* xbase = xz + (size_t)b*L_*E_ + d;   // x part = first DI_ of E_
    float acc = cb[d];
#pragma unroll
    for (int k = 0; k < 4; ++k) {
        int t = l - 3 + k;
        if (t >= 0) acc = fmaf(cw[d*4 + k], bf2f(xbase[(size_t)t*E_]), acc);
    }
    xc_f[(size_t)(b*L_ + l)*DI_ + d] = f2bf(silu_f(acc));
    float accb = cbb[d];
#pragma unroll
    for (int k = 0; k < 4; ++k) {
        int t = l - 3 + k;
        if (t >= 0) accb = fmaf(cwb[d*4 + k], bf2f(xbase[(size_t)(L_ - 1 - t)*E_]), accb);
    }
    xc_b[(size_t)(b*L_ + l)*DI_ + d] = f2bf(silu_f(accb));
}

// ---------------- chunked parallel scan (delta folded in) ----------------
// Phase 1: per-chunk local scan -> hloc, aprod. grid (NC_, B_, 2), DI_ threads.
__global__ void scan_part1(const ushort_t* __restrict__ xc_f, const ushort_t* __restrict__ xc_b,
                           const float* __restrict__ xdbl_f, const float* __restrict__ xdbl_b,
                           const float* __restrict__ Wdt, const float* __restrict__ bdt,
                           const float* __restrict__ Wdtb, const float* __restrict__ bdtb,
                           const float* __restrict__ Alog, const float* __restrict__ Alogb,
                           float* __restrict__ hloc, float* __restrict__ aprod) {
    int c = blockIdx.x, b = blockIdx.y, br = blockIdx.z;
    int d = threadIdx.x;
    const ushort_t* xc = br ? xc_b : xc_f;
    const float* xd = br ? xdbl_b : xdbl_f;
    const float* Wd = br ? Wdtb : Wdt;
    const float* bd = br ? bdtb : bdt;
    const float* Al = br ? Alogb : Alog;
    __shared__ float su[LC_][DI_];
    __shared__ float sdt[LC_][R_];
    __shared__ float sB[LC_][N_];
    int lbeg = c * LC_;
    int lend = min(lbeg + LC_, L_);
    int len = lend - lbeg;
    for (int l2 = 0; l2 < len; ++l2) {
        size_t row = (size_t)b*L_ + lbeg + l2;
        su[l2][d] = bf2f(xc[row*DI_ + d]);
    }
    for (int idx = d; idx < len*N_; idx += DI_) {
        int l2 = idx >> 4, n = idx & 15;
        sB[l2][n] = xd[((size_t)b*L_ + lbeg + l2)*XD + R_ + n];
    }
    for (int idx = d; idx < len*R_; idx += DI_) {
        int l2 = idx / R_, r = idx % R_;
        sdt[l2][r] = xd[((size_t)b*L_ + lbeg + l2)*XD + r];
    }
    __syncthreads();
    float wreg[R_];
#pragma unroll
    for (int r = 0; r < R_; ++r) wreg[r] = Wd[d*R_ + r];
    float bdv = bd[d];
    float a[N_];
#pragma unroll
    for (int n = 0; n < N_; ++n) a[n] = -__expf(Al[d*N_ + n]);
    float h[N_], ap[N_];
#pragma unroll
    for (int n = 0; n < N_; ++n) { h[n] = 0.f; ap[n] = 1.f; }
    for (int l2 = 0; l2 < len; ++l2) {
        float dacc = bdv;
#pragma unroll
        for (int r = 0; r < R_; ++r) dacc = fmaf(wreg[r], sdt[l2][r], dacc);
        float dv = fmaxf(dacc, 0.f) + log1pf(__expf(-fabsf(dacc)));
        float u = su[l2][d], du = dv * u;
#pragma unroll
        for (int n = 0; n < N_; ++n) {
            float e = __expf(dv * a[n]);
            h[n] = fmaf(e, h[n], du * sB[l2][n]);
            ap[n] *= e;
        }
    }
    size_t base = (((size_t)(b*2 + br)*NC_ + c)*N_)*DI_ + d;
#pragma unroll
    for (int n = 0; n < N_; ++n) {
        hloc[base + (size_t)n*DI_]  = h[n];
        aprod[base + (size_t)n*DI_] = ap[n];
    }
}

// Phase 2: serial combine over chunks
__global__ void scan_combine(const float* __restrict__ hloc, const float* __restrict__ aprod,
                             float* __restrict__ hin) {
    int g = blockIdx.x * blockDim.x + threadIdx.x;   // over B_*2*N_*DI_
    int bb = g / (N_ * DI_);
    int rem = g % (N_ * DI_);
    float hrun = 0.f;
    for (int c = 0; c < NC_; ++c) {
        size_t idx = ((size_t)bb*NC_ + c)*N_*DI_ + rem;
        hin[idx] = hrun;
        hrun = fmaf(aprod[idx], hrun, hloc[idx]);
    }
}

// Phase 3: re-scan from hin, emit y = (h.C + Dp*u)*silu(z)  (f32 y for out-proj avg)
__global__ void scan_part3(const ushort_t* __restrict__ xc_f, const ushort_t* __restrict__ xc_b,
                           const float* __restrict__ xdbl_f, const float* __restrict__ xdbl_b,
                           const float* __restrict__ Wdt, const float* __restrict__ bdt,
                           const float* __restrict__ Wdtb, const float* __restrict__ bdtb,
                           const ushort_t* __restrict__ xz,
                           const float* __restrict__ Alog, const float* __restrict__ Alogb,
                           const float* __restrict__ Dpf, const float* __restrict__ Dpb,
                           const float* __restrict__ hin,
                           float* __restrict__ y_f, float* __restrict__ y_b) {
    int c = blockIdx.x, b = blockIdx.y, br = blockIdx.z;
    int d = threadIdx.x;
    const ushort_t* xc = br ? xc_b : xc_f;
    const float* xd = br ? xdbl_b : xdbl_f;
    const float* Wd = br ? Wdtb : Wdt;
    const float* bd = br ? bdtb : bdt;
    const float* Al = br ? Alogb : Alog;
    const float* Dpp = br ? Dpb : Dpf;
    float* y = br ? y_b : y_f;
    __shared__ float su[LC_][DI_];
    __shared__ float sdt[LC_][R_];
    __shared__ float sB[LC_][N_];
    __shared__ float sC[LC_][N_];
    int lbeg = c * LC_;
    int lend = min(lbeg + LC_, L_);
    int len = lend - lbeg;
    for (int l2 = 0; l2 < len; ++l2) {
        size_t row = (size_t)b*L_ + lbeg + l2;
        su[l2][d] = bf2f(xc[row*DI_ + d]);
    }
    for (int idx = d; idx < len*N_; idx += DI_) {
        int l2 = idx >> 4, n = idx & 15;
        size_t row = (size_t)b*L_ + lbeg + l2;
        sB[l2][n] = xd[row*XD + R_ + n];
        sC[l2][n] = xd[row*XD + R_ + N_ + n];
    }
    for (int idx = d; idx < len*R_; idx += DI_) {
        int l2 = idx / R_, r = idx % R_;
        sdt[l2][r] = xd[((size_t)b*L_ + lbeg + l2)*XD + r];
    }
    __syncthreads();
    float wreg[R_];
#pragma unroll
    for (int r = 0; r < R_; ++r) wreg[r] = Wd[d*R_ + r];
    float bdv = bd[d];
    float a[N_];
#pragma unroll
    for (int n = 0; n < N_; ++n) a[n] = -__expf(Al[d*N_ + n]);
    float h[N_];
    size_t hbase = (((size_t)(b*2 + br)*NC_ + c)*N_)*DI_ + d;
#pragma unroll
    for (int n = 0; n < N_; ++n) h[n] = hin[hbase + (size_t)n*DI_];
    float dpv = Dpp[d];
    for (int l2 = 0; l2 < len; ++l2) {
        float dacc = bdv;
#pragma unroll
        for (int r = 0; r < R_; ++r) dacc = fmaf(wreg[r], sdt[l2][r], dacc);
        float dv = fmaxf(dacc, 0.f) + log1pf(__expf(-fabsf(dacc)));
        float u = su[l2][d], du = dv * u;
        float yv = 0.f;
#pragma unroll
        for (int n = 0; n < N_; ++n) {
            float e = __expf(dv * a[n]);
            h[n] = fmaf(e, h[n], du * sB[l2][n]);
            yv = fmaf(h[n], sC[l2][n], yv);
        }
        yv = fmaf(dpv, u, yv);
        int lo = br ? (L_ - 1 - (lbeg + l2)) : (lbeg + l2);
        float zv = bf2f(xz[((size_t)b*L_ + lo)*E_ + DI_ + d]);
        y[((size_t)b*L_ + lo)*DI_ + d] = yv * silu_f(zv);
    }
}

extern "C" void kernel_launch(void* const* d_in, const int* in_sizes, int n_in,
                              void* d_out, int out_size, void* d_ws, size_t ws_size,
                              hipStream_t stream) {
    const float* xs     = (const float*)d_in[0];
    const float* xt     = (const float*)d_in[1];
    const float* pw     = (const float*)d_in[2];
    const float* pb     = (const float*)d_in[3];
    const float* cls    = (const float*)d_in[4];
    const float* pos    = (const float*)d_in[5];
    const float* Win    = (const float*)d_in[6];
    const float* convw  = (const float*)d_in[7];
    const float* convb  = (const float*)d_in[8];
    const float* Wx     = (const float*)d_in[9];
    const float* Wdt    = (const float*)d_in[10];
    const float* bdt    = (const float*)d_in[11];
    const float* Alog   = (const float*)d_in[12];
    const float* Dp     = (const float*)d_in[13];
    const float* convwb = (const float*)d_in[14];
    const float* convbb = (const float*)d_in[15];
    const float* Wxb    = (const float*)d_in[16];
    const float* Wdtb   = (const float*)d_in[17];
    const float* bdtb   = (const float*)d_in[18];
    const float* Alogb  = (const float*)d_in[19];
    const float* Dpb    = (const float*)d_in[20];
    const float* Wout   = (const float*)d_in[21];
    const float* normw  = (const float*)d_in[22];
    const float* normwf = (const float*)d_in[23];
    float* out = (float*)d_out;

    float* ws = (float*)d_ws;
    size_t off = 0;
    auto alloc = [&](size_t nfloats) { float* p = ws + off; off += nfloats; return p; };
    const size_t BL = (size_t)B_ * L_;
    const size_t CHNK = (size_t)B_ * 2 * NC_ * N_ * DI_;

    float*    residual = alloc(BL * D_);
    float*    hidden   = alloc(BL * D_);
    ushort_t* hn_bf    = (ushort_t*)alloc(BL * D_ / 2);
    ushort_t* xzb_bf   = (ushort_t*)alloc(BL * E_ / 2);
    ushort_t* xcf_bf   = (ushort_t*)alloc(BL * DI_ / 2);
    ushort_t* xcb_bf   = (ushort_t*)alloc(BL * DI_ / 2);
    float*    xdbl_f   = alloc(BL * XD);
    float*    xdbl_b   = alloc(BL * XD);
    float*    y_f      = alloc(BL * DI_);
    float*    y_b      = alloc(BL * DI_);
    float*    hloc     = alloc(CHNK);
    float*    aprod    = alloc(CHNK);
    float*    hin      = alloc(CHNK);
    // bf16 weights
    ushort_t* pw_bf    = (ushort_t*)alloc((size_t)D_ * 768 / 2);
    ushort_t* Win_bf   = (ushort_t*)alloc((size_t)DEPTH_ * E_ * D_ / 2);
    ushort_t* Wx_bf    = (ushort_t*)alloc((size_t)DEPTH_ * XD * DI_ / 2);
    ushort_t* Wxb_bf   = (ushort_t*)alloc((size_t)DEPTH_ * XD * DI_ / 2);
    ushort_t* Wout_bf  = (ushort_t*)alloc((size_t)DEPTH_ * D_ * DI_ / 2);
    (void)ws_size; (void)in_sizes; (void)n_in; (void)out_size;

    // one-time (per launch) weight conversions
    cvt_bf16<<<dim3(64),  dim3(256), 0, stream>>>(pw,   pw_bf,   D_ * 768);
    cvt_bf16<<<dim3(2048), dim3(256), 0, stream>>>(Win,  Win_bf,  DEPTH_ * E_ * D_);
    cvt_bf16<<<dim3(512), dim3(256), 0, stream>>>(Wx,   Wx_bf,   DEPTH_ * XD * DI_);
    cvt_bf16<<<dim3(512), dim3(256), 0, stream>>>(Wxb,  Wxb_bf,  DEPTH_ * XD * DI_);
    cvt_bf16<<<dim3(1024), dim3(256), 0, stream>>>(Wout, Wout_bf, DEPTH_ * D_ * DI_);

    // patch embed: pmat (bf16) in y_f region, tokmat (f32) in y_b region
    ushort_t* pmat   = (ushort_t*)y_f;    // 983040 ushorts <= y_f floats*2
    float*    tokmat = y_b;               // 245760 floats  <= y_b
    im2col_kernel<<<dim3(B_ * 320), dim3(256), 0, stream>>>(xs, xt, pmat);
    mfma_gemm<2, 2, 2, 2, 0><<<dim3(3, 20), dim3(256), 0, stream>>>(
        pmat, nullptr, nullptr, pw_bf, tokmat, B_ * 320, D_, 768);
    tok_scatter<<<dim3(B_ * L_), dim3(192), 0, stream>>>(tokmat, pb, cls, pos, hidden, residual);

    for (int layer = 0; layer < DEPTH_; ++layer) {
        const ushort_t* Win_l  = Win_bf  + (size_t)layer * E_ * D_;
        const ushort_t* Wx_l   = Wx_bf   + (size_t)layer * XD * DI_;
        const ushort_t* Wxb_l  = Wxb_bf  + (size_t)layer * XD * DI_;
        const ushort_t* Wout_l = Wout_bf + (size_t)layer * D_ * DI_;
        const float* cw_l    = convw  + (size_t)layer * DI_ * 4;
        const float* cb_l    = convb  + (size_t)layer * DI_;
        const float* cwb_l   = convwb + (size_t)layer * DI_ * 4;
        const float* cbb_l   = convbb + (size_t)layer * DI_;
        const float* Wdt_l   = Wdt    + (size_t)layer * DI_ * R_;
        const float* Wdtb_l  = Wdtb   + (size_t)layer * DI_ * R_;
        const float* bdt_l   = bdt    + (size_t)layer * DI_;
        const float* bdtb_l  = bdtb   + (size_t)layer * DI_;
        const float* Alog_l  = Alog   + (size_t)layer * DI_ * N_;
        const float* Alogb_l = Alogb  + (size_t)layer * DI_ * N_;
        const float* Dp_l    = Dp     + (size_t)layer * DI_;
        const float* Dpb_l   = Dpb    + (size_t)layer * DI_;
        const float* normw_l = normw  + (size_t)layer * D_;

        prenorm_kernel<<<dim3((int)BL), dim3(256), 0, stream>>>(residual, hidden, normw_l, hn_bf);
        // in-proj: M=1284, N=768, K=192 -> xzb bf16? (C is f32; we need bf16 xzb)
        // C written f32 would need extra convert; instead write f32 into a temp and
        // convert in conv? Simpler: keep C f32 path: use hloc as temp f32 xzb then
        // conv converts. But conv also needs z later... -> write bf16 via epilogue:
        // we instead store f32 xzb in hloc+aprod region? They are free until scan.
        // Simplest correct: xzb f32 temp in (hloc) region [BL*E_=986112 <= CHNK=1032192]
        mfma_gemm<2, 2, 2, 2, 0><<<dim3(12, 21), dim3(256), 0, stream>>>(
            hn_bf, nullptr, nullptr, Win_l, hloc /*xzb f32 temp*/, (int)BL, E_, D_);
        // convert xzb f32 -> bf16 (needed by conv + scan z); fused into cvt kernel
        cvt_bf16<<<dim3(1024), dim3(256), 0, stream>>>(hloc, xzb_bf, (int)(BL * E_));
        conv_kernel<<<dim3((int)BL), dim3(DI_), 0, stream>>>(xzb_bf, cw_l, cb_l, cwb_l, cbb_l, xcf_bf, xcb_bf);
        // xdbl (both dirs): M=1284, N=44, K=384
        mfma_gemm_dual<<<dim3(1, 21, 2), dim3(256), 0, stream>>>(
            xcf_bf, Wx_l, xdbl_f, xcb_bf, Wxb_l, xdbl_b, (int)BL, XD, DI_);
        scan_part1<<<dim3(NC_, B_, 2), dim3(DI_), 0, stream>>>(
            xcf_bf, xcb_bf, xdbl_f, xdbl_b, Wdt_l, bdt_l, Wdtb_l, bdtb_l,
            Alog_l, Alogb_l, hloc, aprod);
        scan_combine<<<dim3((B_*2*N_*DI_)/256), dim3(256), 0, stream>>>(hloc, aprod, hin);
        scan_part3<<<dim3(NC_, B_, 2), dim3(DI_), 0, stream>>>(
            xcf_bf, xcb_bf, xdbl_f, xdbl_b, Wdt_l, bdt_l, Wdtb_l, bdtb_l, xzb_bf,
            Alog_l, Alogb_l, Dp_l, Dpb_l, hin, y_f, y_b);
        // out-proj: M=1284, N=192, K=384, avg(y_f, y_b) on the fly
        mfma_gemm<2, 2, 2, 2, 1><<<dim3(3, 21), dim3(256), 0, stream>>>(
            nullptr, y_f, y_b, Wout_l, hidden, (int)BL, D_, DI_);
    }

    final_kernel<<<dim3((int)BL), dim3(256), 0, stream>>>(residual, hidden, normwf, out);
}